// Round 2
// baseline (159.576 us; speedup 1.0000x reference)
//
#include <hip/hip_runtime.h>

#define KS 10
#define NT 256
#define CHUNK 4096   // level-0 samples per block (useful, excl. halo)

// Extended (halo) ranges per block, derived from cascaded 10-tap stride-2 support:
//   x   : [x0-60, x0+4156)   count 4216
//   a1  : [o1-28, o1+2076)   count 2104
//   a2  : [o2-12, o2+1036)   count 1048
//   a3  : [o3-4,  o3+516 )   count 520
//   a4  : [o4,    o4+256 )   count 256

struct OutPtrs { float* a0; float* a1; float* a2; float* a3;
                 float* d0; float* d1; float* d2; float* d3; };

// read level input at virtual index v with per-level antireflect (only at row edges)
__device__ __forceinline__ float rdIn(const float* __restrict__ s, int base, int v,
                                      int Lin, bool refl) {
    if (refl) {
        if (v < 0)    return 2.0f * s[0 - base]         - s[(-v) - base];
        if (v >= Lin) return 2.0f * s[(Lin - 1) - base] - s[(2 * Lin - 2 - v) - base];
    }
    return s[v - base];
}

__device__ __forceinline__ void level_pass(
    const float* __restrict__ sIn, int bIn, int Lin, bool refl,
    float* __restrict__ sOut, int bOut, int extN,
    int Lout, int oOut, int ownN,
    float* __restrict__ agp, float* __restrict__ dgp,   // global row bases
    const float* h, const float* g, int tid)
{
    for (int t = tid; t < extN; t += NT) {
        int v = bOut + t;                   // level output index (virtual)
        if (v < 0 || v >= Lout) continue;   // out-of-range slots stay garbage; never read directly
        float xin[KS];
#pragma unroll
        for (int k = 0; k < KS; ++k) xin[k] = rdIn(sIn, bIn, 2 * v - 4 + k, Lin, refl);
        float aa = 0.0f, dd = 0.0f;
#pragma unroll
        for (int k = 0; k < KS; ++k) { aa = fmaf(xin[k], h[k], aa); dd = fmaf(xin[k], g[k], dd); }
        if (sOut) sOut[t] = aa;
        unsigned rel = (unsigned)(v - oOut);
        if (rel < (unsigned)ownN) { agp[v] = aa; dgp[v] = dd; }
    }
}

__global__ __launch_bounds__(NT) void dwt_fused_kernel(
    const float* __restrict__ x, const float* __restrict__ hptr, OutPtrs op, int L0)
{
    const int row = blockIdx.y;
    const int c   = blockIdx.x;
    const int nc  = gridDim.x;
    const int tid = threadIdx.x;
    const bool edge = (c == 0) || (c == nc - 1);

    const int L1 = L0 >> 1, L2 = L0 >> 2, L3 = L0 >> 3, L4 = L0 >> 4;
    const int o1 = c * (CHUNK >> 1), o2 = c * (CHUNK >> 2),
              o3 = c * (CHUNK >> 3), o4 = c * (CHUNK >> 4);
    const int s0 = c * CHUNK - 60;
    const int s1 = o1 - 28, s2 = o2 - 12, s3 = o3 - 4;

    __shared__ float sx [4216];
    __shared__ float sa1[2104];
    __shared__ float sa2[1048];
    __shared__ float sa3[520];

    float h[KS], g[KS];
#pragma unroll
    for (int k = 0; k < KS; ++k) h[k] = hptr[k];
#pragma unroll
    for (int k = 0; k < KS; ++k) g[k] = ((k & 1) ? -1.0f : 1.0f) * h[KS - 1 - k];

    // ---- stage x chunk (+halo) into LDS; reflect values pre-applied at row edges ----
    const float* xr = x + (size_t)row * (size_t)L0;
    if (!edge) {
        // s0 = c*4096-60 -> (s0*4) is 16B-aligned (240 = 15*16)
        const float4* src = reinterpret_cast<const float4*>(xr + s0);
        float4* dst = reinterpret_cast<float4*>(sx);
        for (int t = tid; t < 4216 / 4; t += NT) dst[t] = src[t];
    } else {
        for (int t = tid; t < 4216; t += NT) {
            int m = s0 + t;
            float v;
            if (m < 0)        v = 2.0f * xr[0]      - xr[-m];
            else if (m >= L0) v = 2.0f * xr[L0 - 1] - xr[2 * L0 - 2 - m];
            else              v = xr[m];
            sx[t] = v;
        }
    }
    __syncthreads();

    // ---- cascade: level 1..4 ----
    // level 1: sx is fully valid (reflect pre-applied) -> refl=false
    level_pass(sx,  s0, L0, false, sa1, s1, 2104, L1, o1, CHUNK >> 1,
               op.a0 + (size_t)row * L1, op.d0 + (size_t)row * L1, h, g, tid);
    __syncthreads();
    level_pass(sa1, s1, L1, edge,  sa2, s2, 1048, L2, o2, CHUNK >> 2,
               op.a1 + (size_t)row * L2, op.d1 + (size_t)row * L2, h, g, tid);
    __syncthreads();
    level_pass(sa2, s2, L2, edge,  sa3, s3, 520,  L3, o3, CHUNK >> 3,
               op.a2 + (size_t)row * L3, op.d2 + (size_t)row * L3, h, g, tid);
    __syncthreads();
    level_pass(sa3, s3, L3, edge,  nullptr, o4, 256, L4, o4, CHUNK >> 4,
               op.a3 + (size_t)row * L4, op.d3 + (size_t)row * L4, h, g, tid);
}

extern "C" void kernel_launch(void* const* d_in, const int* in_sizes, int n_in,
                              void* d_out, int out_size, void* d_ws, size_t ws_size,
                              hipStream_t stream) {
    (void)n_in; (void)d_ws; (void)ws_size; (void)out_size;

    const float* signal = (const float*)d_in[0];
    const float* h      = (const float*)d_in[1];
    float* out = (float*)d_out;

    const int L0 = 65536;
    const int R  = in_sizes[0] / L0;   // 8*64 = 512 rows
    const int LEVELS = 4;

    size_t s_off[4], d_off[4];
    {
        size_t off = 0;
        int L = L0;
        for (int l = 0; l < LEVELS; ++l) { s_off[l] = off; off += (size_t)R * (size_t)(L >> 1); L >>= 1; }
        L = L0;
        for (int l = 0; l < LEVELS; ++l) { d_off[l] = off; off += (size_t)R * (size_t)(L >> 1); L >>= 1; }
    }

    OutPtrs op;
    op.a0 = out + s_off[0]; op.a1 = out + s_off[1]; op.a2 = out + s_off[2]; op.a3 = out + s_off[3];
    op.d0 = out + d_off[0]; op.d1 = out + d_off[1]; op.d2 = out + d_off[2]; op.d3 = out + d_off[3];

    dim3 grid(L0 / CHUNK, R);   // 16 x 512 = 8192 blocks
    dim3 block(NT);
    dwt_fused_kernel<<<grid, block, 0, stream>>>(signal, h, op, L0);
}

// Round 3
// 78.452 us; speedup vs baseline: 2.0341x; 2.0341x over previous
//
#include <hip/hip_runtime.h>

#define KS 10
#define NT 256
#define CHUNK 2048   // level-0 samples per block (excl. halo)

// Compile-time level geometry (CHUNK=2048):
//  x  ext: [x0-60,  x0+2108)  count 2168   (pad 60 each side)
//  a1 ext: [o1-28,  o1+1052)  count 1080   pad 28, own 1024
//  a2 ext: [o2-12,  o2+524 )  count 536    pad 12, own 512
//  a3 ext: [o3-4,   o3+260 )  count 264    pad 4,  own 256
//  a4     : own only          count 128
// Input slot identity: output slot t at any level reads input slots [2t, 2t+10).

struct OutPtrs { float* a[4]; float* d[4]; };

template<int EXT, bool LAST>
__device__ __forceinline__ void level_pass(const float* __restrict__ sIn,
                                           float* __restrict__ sOut,
                                           const float* h, const float* g,
                                           float* dreg, float* areg, int tid)
{
    constexpr int ITERS = (EXT + NT - 1) / NT;
#pragma unroll
    for (int i = 0; i < ITERS; ++i) {
        const int t = tid + i * NT;
        if (t < EXT) {
            float aa = 0.0f, dd = 0.0f;
#pragma unroll
            for (int k = 0; k < KS; ++k) {
                const float xv = sIn[2 * t + k];
                aa = fmaf(xv, h[k], aa);
                dd = fmaf(xv, g[k], dd);
            }
            if (LAST) areg[i] = aa; else sOut[t] = aa;
            dreg[i] = dd;
        }
    }
}

// patch antireflect halo slots of an LDS level buffer (edge blocks only)
__device__ __forceinline__ void patch(float* sa, int P, int N, bool left, bool right, int tid)
{
    if (left && tid < P)
        sa[tid] = 2.0f * sa[P] - sa[2 * P - tid];
    if (right && tid < P) {
        const int E = P + N - 1;
        const int t = P + N + tid;
        sa[t] = 2.0f * sa[E] - sa[2 * E - t];
    }
}

template<int ITERS, int PADO, int OWN>
__device__ __forceinline__ void store_d(float* __restrict__ grow, int oOut,
                                        const float* dreg, int tid)
{
#pragma unroll
    for (int i = 0; i < ITERS; ++i) {
        const int t = tid + i * NT;
        if (t >= PADO && t < PADO + OWN) grow[oOut + t - PADO] = dreg[i];
    }
}

__global__ __launch_bounds__(NT) void dwt_fused_kernel(
    const float* __restrict__ x, const float* __restrict__ hptr, OutPtrs op, int L0)
{
    const int row = blockIdx.y;
    const int c   = blockIdx.x;
    const int nc  = gridDim.x;
    const int tid = threadIdx.x;
    const bool left  = (c == 0);
    const bool right = (c == nc - 1);

    const int L1 = L0 >> 1, L2 = L0 >> 2, L3 = L0 >> 3, L4 = L0 >> 4;
    const int o1 = c * (CHUNK >> 1), o2 = c * (CHUNK >> 2),
              o3 = c * (CHUNK >> 3), o4 = c * (CHUNK >> 4);
    const int s0 = c * CHUNK - 60;

    __shared__ float sx [2168];
    __shared__ float sa1[1080];
    __shared__ float sa2[536];
    __shared__ float sa3[264];

    float h[KS], g[KS];
#pragma unroll
    for (int k = 0; k < KS; ++k) h[k] = hptr[k];
#pragma unroll
    for (int k = 0; k < KS; ++k) g[k] = ((k & 1) ? -1.0f : 1.0f) * h[KS - 1 - k];

    // ---- stage x chunk (+halo) into LDS, fully vectorized for ALL blocks ----
    const float* xr = x + (size_t)row * (size_t)L0;
    {
        const int tlo = left ? 60 : 0;          // valid slot range [tlo, thi)
        const int thi = right ? 2108 : 2168;    // (slot t holds x[s0+t])
        const int nf4 = (thi - tlo) >> 2;       // both bounds 16B-aligned
        const float4* src = reinterpret_cast<const float4*>(xr + s0 + tlo);
        float4* dst = reinterpret_cast<float4*>(sx + tlo);
        for (int j = tid; j < nf4; j += NT) dst[j] = src[j];
    }
    __syncthreads();
    // x-halo antireflect patch (edge blocks only)
    if (left && tid < 60)
        sx[tid] = 2.0f * sx[60] - sx[120 - tid];
    if (right && tid < 60) {
        const int t = 2108 + tid;               // x[L0-1] is slot 2107
        sx[t] = 2.0f * sx[2107] - sx[4214 - t];
    }
    __syncthreads();

    // ---- cascade, all global writes deferred to the end ----
    float d1[5], d2[3], d3[2], d4[1], a4[1];

    level_pass<1080, false>(sx,  sa1, h, g, d1, nullptr, tid);
    __syncthreads();
    patch(sa1, 28, 1024, left, right, tid);
    __syncthreads();

    level_pass<536, false>(sa1, sa2, h, g, d2, nullptr, tid);
    __syncthreads();
    patch(sa2, 12, 512, left, right, tid);
    __syncthreads();

    level_pass<264, false>(sa2, sa3, h, g, d3, nullptr, tid);
    __syncthreads();
    patch(sa3, 4, 256, left, right, tid);
    __syncthreads();

    level_pass<128, true>(sa3, nullptr, h, g, d4, a4, tid);

    // ---- epilogue: write everything (no barriers after this point) ----
    const size_t r1 = (size_t)row * L1, r2 = (size_t)row * L2,
                 r3 = (size_t)row * L3, r4 = (size_t)row * L4;

    // a1..a3 from LDS own ranges as float4 (halo offsets 28/12/4 are 16B-aligned)
    reinterpret_cast<float4*>(op.a[0] + r1 + o1)[tid] =
        reinterpret_cast<const float4*>(sa1 + 28)[tid];                 // 256 f4 = 1024
    if (tid < 128)
        reinterpret_cast<float4*>(op.a[1] + r2 + o2)[tid] =
            reinterpret_cast<const float4*>(sa2 + 12)[tid];             // 512
    if (tid < 64)
        reinterpret_cast<float4*>(op.a[2] + r3 + o3)[tid] =
            reinterpret_cast<const float4*>(sa3 + 4)[tid];              // 256
    if (tid < 128)
        (op.a[3] + r4 + o4)[tid] = a4[0];                               // 128 from reg

    store_d<5, 28, 1024>(op.d[0] + r1, o1, d1, tid);
    store_d<3, 12, 512 >(op.d[1] + r2, o2, d2, tid);
    store_d<2, 4,  256 >(op.d[2] + r3, o3, d3, tid);
    if (tid < 128) (op.d[3] + r4 + o4)[tid] = d4[0];
}

extern "C" void kernel_launch(void* const* d_in, const int* in_sizes, int n_in,
                              void* d_out, int out_size, void* d_ws, size_t ws_size,
                              hipStream_t stream) {
    (void)n_in; (void)d_ws; (void)ws_size; (void)out_size;

    const float* signal = (const float*)d_in[0];
    const float* h      = (const float*)d_in[1];
    float* out = (float*)d_out;

    const int L0 = 65536;
    const int R  = in_sizes[0] / L0;   // 512 rows
    const int LEVELS = 4;

    size_t s_off[4], d_off[4];
    {
        size_t off = 0;
        int L = L0;
        for (int l = 0; l < LEVELS; ++l) { s_off[l] = off; off += (size_t)R * (size_t)(L >> 1); L >>= 1; }
        L = L0;
        for (int l = 0; l < LEVELS; ++l) { d_off[l] = off; off += (size_t)R * (size_t)(L >> 1); L >>= 1; }
    }

    OutPtrs op;
    for (int l = 0; l < LEVELS; ++l) { op.a[l] = out + s_off[l]; op.d[l] = out + d_off[l]; }

    dim3 grid(L0 / CHUNK, R);   // 32 x 512 = 16384 blocks
    dim3 block(NT);
    dwt_fused_kernel<<<grid, block, 0, stream>>>(signal, h, op, L0);
}